// Round 1
// baseline (931.671 us; speedup 1.0000x reference)
//
#include <hip/hip_runtime.h>
#include <math.h>

#define EPS 1e-5f
#define INV_N (1.0f / 1024.0f)

// ---- sizes ----
// B=1024, S=50, DIM=300, VOCAB=200000, N_LANGS=2
// out layout: prob[1024] @0, o1[1024*300] @1024, o2 @308224

// ---- workspace layout (floats) ----
// buf0: 614400   (x -> z2 -> y4)
// buf1: 614400   (z1 -> y3)
// buf2: 922624   (nxt)
// stats: 3400
static const size_t OFF_BUF0 = 0;
static const size_t OFF_BUF1 = 614400;
static const size_t OFF_BUF2 = 1228800;
static const size_t OFF_STATS = 2151424;
// stats sub-offsets (relative to stats base)
static const int S1_SUM = 0, S1_SQ = 600;     // 2 sides x 300
static const int S2_SUM = 1200, S2_SQ = 1800; // 2 sides x 300
static const int S3_SUM = 2400, S3_SQ = 2800; // 1 side x 400
static const int S4_SUM = 3200, S4_SQ = 3300; // 1 side x 100
static const int STATS_TOTAL = 3400;

// ---------------------------------------------------------------------------
// K1: embedding gather + sum-pool. grid 2048 (side*1024+b), block 128.
// Block 0 also zeroes the stat buffers (ws is poisoned before every launch).
// ---------------------------------------------------------------------------
__global__ __launch_bounds__(128) void gather_kernel(
    const int* __restrict__ langs1, const int* __restrict__ sents1,
    const int* __restrict__ langs2, const int* __restrict__ sents2,
    const float* __restrict__ tables, float* __restrict__ x,
    float* __restrict__ stats)
{
    int idx = blockIdx.x, t = threadIdx.x;
    if (idx == 0) {
        for (int i = t; i < STATS_TOTAL; i += 128) stats[i] = 0.f;
    }
    int side = idx >> 10, b = idx & 1023;
    const int* langs = side ? langs2 : langs1;
    const int* sents = side ? sents2 : sents1;
    __shared__ int toks[50];
    if (t < 50) toks[t] = sents[b * 50 + t];
    __syncthreads();
    const float* base = tables + (size_t)langs[b] * (200000ull * 300ull);
    float a0 = 0.f, a1 = 0.f, a2 = 0.f;
    #pragma unroll 5
    for (int s = 0; s < 50; s++) {
        const float* row = base + (size_t)toks[s] * 300;
        a0 += row[t];
        a1 += row[t + 128];
        if (t < 44) a2 += row[t + 256];
    }
    float* xr = x + (size_t)idx * 300;
    xr[t] = a0;
    xr[t + 128] = a1;
    if (t < 44) xr[t + 256] = a2;
}

// ---------------------------------------------------------------------------
// Generic fp32 GEMM: C[M][N] = act(A)[M][K] @ W[N][K]^T + bias.
// If inSum != null, A-loads get BN(stats over 1024-row sides)+ReLU applied.
// Per-block column sums/sumsqs of C are atomically accumulated into
// outSum/outSq (side = row-block >= 1024). Tile 64x64, 256 thr, 4x4/thread.
// ---------------------------------------------------------------------------
__global__ __launch_bounds__(256) void gemm_bn(
    const float* __restrict__ A, const float* __restrict__ W,
    const float* __restrict__ bias, float* __restrict__ C,
    const float* __restrict__ inSum, const float* __restrict__ inSq,
    float* __restrict__ outSum, float* __restrict__ outSq,
    int M, int N, int K)
{
    __shared__ float As[16][68];
    __shared__ float Bs[16][68];
    __shared__ float redS[16][64];
    __shared__ float redQ[16][64];

    int tid = threadIdx.x;
    int tx = tid & 15, ty = tid >> 4;
    int r0 = blockIdx.x * 64, c0 = blockIdx.y * 64;
    int sideOut = (r0 >= 1024) ? 1 : 0;

    float acc[4][4] = {{0.f}};

    for (int k0 = 0; k0 < K; k0 += 16) {
        #pragma unroll
        for (int i = 0; i < 4; i++) {
            int e = tid + i * 256;
            int row = e >> 4, k = e & 15;
            int kg = k0 + k;
            float v = 0.f;
            if (kg < K) {
                v = A[(size_t)(r0 + row) * K + kg];
                if (inSum) {
                    int side = ((r0 + row) >= 1024) ? 1 : 0;
                    float m = inSum[side * K + kg] * INV_N;
                    float var = inSq[side * K + kg] * INV_N - m * m;
                    v = (v - m) * rsqrtf(var + EPS);
                    v = v > 0.f ? v : 0.f;
                }
            }
            As[k][row] = v;
            int cg = c0 + row;  // same flat index reused for the W tile
            float w = (kg < K && cg < N) ? W[(size_t)cg * K + kg] : 0.f;
            Bs[k][row] = w;
        }
        __syncthreads();
        #pragma unroll
        for (int kk = 0; kk < 16; kk++) {
            float4 a4 = *(const float4*)&As[kk][ty * 4];
            float4 b4 = *(const float4*)&Bs[kk][tx * 4];
            float av[4] = {a4.x, a4.y, a4.z, a4.w};
            float bv[4] = {b4.x, b4.y, b4.z, b4.w};
            #pragma unroll
            for (int i = 0; i < 4; i++)
                #pragma unroll
                for (int j = 0; j < 4; j++)
                    acc[i][j] += av[i] * bv[j];
        }
        __syncthreads();
    }

    float ps[4] = {0.f, 0.f, 0.f, 0.f}, pq[4] = {0.f, 0.f, 0.f, 0.f};
    #pragma unroll
    for (int i = 0; i < 4; i++) {
        int r = r0 + ty * 4 + i;
        #pragma unroll
        for (int j = 0; j < 4; j++) {
            int c = c0 + tx * 4 + j;
            if (c < N) {
                float v = acc[i][j] + bias[c];
                C[(size_t)r * N + c] = v;
                ps[j] += v;
                pq[j] += v * v;
            }
        }
    }
    #pragma unroll
    for (int j = 0; j < 4; j++) {
        redS[ty][tx * 4 + j] = ps[j];
        redQ[ty][tx * 4 + j] = pq[j];
    }
    __syncthreads();
    if (tid < 64) {
        float s = 0.f, q = 0.f;
        #pragma unroll
        for (int t = 0; t < 16; t++) { s += redS[t][tid]; q += redQ[t][tid]; }
        int c = c0 + tid;
        if (c < N && outSum) {
            atomicAdd(&outSum[sideOut * N + c], s);
            atomicAdd(&outSq[sideOut * N + c], q);
        }
    }
}

// ---------------------------------------------------------------------------
// K4: BN2+ReLU -> o1,o2 (to d_out), build nxt = [o1,o2,|o1-o2|,cor].
// grid 1024, block 128.
// ---------------------------------------------------------------------------
__global__ __launch_bounds__(128) void pair_kernel(
    const float* __restrict__ z2, const float* __restrict__ sSum,
    const float* __restrict__ sSq, float* __restrict__ out,
    float* __restrict__ nxt)
{
    int b = blockIdx.x, t = threadIdx.x;
    __shared__ float red[128];
    float dot = 0.f;
    for (int d = t; d < 300; d += 128) {
        float m1 = sSum[d] * INV_N;
        float v1 = sSq[d] * INV_N - m1 * m1;
        float m2 = sSum[300 + d] * INV_N;
        float v2 = sSq[300 + d] * INV_N - m2 * m2;
        float a1 = (z2[(size_t)b * 300 + d] - m1) * rsqrtf(v1 + EPS);
        a1 = a1 > 0.f ? a1 : 0.f;
        float a2 = (z2[(size_t)(1024 + b) * 300 + d] - m2) * rsqrtf(v2 + EPS);
        a2 = a2 > 0.f ? a2 : 0.f;
        out[1024 + (size_t)b * 300 + d] = a1;
        out[308224 + (size_t)b * 300 + d] = a2;
        nxt[(size_t)b * 901 + d] = a1;
        nxt[(size_t)b * 901 + 300 + d] = a2;
        nxt[(size_t)b * 901 + 600 + d] = fabsf(a1 - a2);
        dot += a1 * a2;
    }
    red[t] = dot;
    __syncthreads();
    if (t == 0) {
        float s = 0.f;
        for (int i = 0; i < 128; i++) s += red[i];
        nxt[(size_t)b * 901 + 900] = s;
    }
}

// ---------------------------------------------------------------------------
// K7: BN4+ReLU, dot with w5, + b5, sigmoid -> prob. grid 1024, block 64.
// ---------------------------------------------------------------------------
__global__ __launch_bounds__(64) void final_kernel(
    const float* __restrict__ y4, const float* __restrict__ sSum,
    const float* __restrict__ sSq, const float* __restrict__ w5,
    const float* __restrict__ b5, float* __restrict__ out)
{
    int b = blockIdx.x, l = threadIdx.x;
    float acc = 0.f;
    for (int j = l; j < 100; j += 64) {
        float m = sSum[j] * INV_N;
        float var = sSq[j] * INV_N - m * m;
        float v = (y4[(size_t)b * 100 + j] - m) * rsqrtf(var + EPS);
        v = v > 0.f ? v : 0.f;
        acc += v * w5[j];
    }
    #pragma unroll
    for (int off = 32; off; off >>= 1) acc += __shfl_down(acc, off);
    if (l == 0) out[b] = 1.f / (1.f + expf(-(acc + b5[0])));
}

// ---------------------------------------------------------------------------
extern "C" void kernel_launch(void* const* d_in, const int* in_sizes, int n_in,
                              void* d_out, int out_size, void* d_ws, size_t ws_size,
                              hipStream_t stream)
{
    const int* langs1 = (const int*)d_in[0];
    const int* sents1 = (const int*)d_in[1];
    const int* langs2 = (const int*)d_in[2];
    const int* sents2 = (const int*)d_in[3];
    const float* tables = (const float*)d_in[4];
    const float* w1 = (const float*)d_in[5];
    const float* b1 = (const float*)d_in[6];
    const float* w2 = (const float*)d_in[7];
    const float* b2 = (const float*)d_in[8];
    const float* w3 = (const float*)d_in[9];
    const float* b3 = (const float*)d_in[10];
    const float* w4 = (const float*)d_in[11];
    const float* b4 = (const float*)d_in[12];
    const float* w5 = (const float*)d_in[13];
    const float* b5 = (const float*)d_in[14];

    float* ws = (float*)d_ws;
    float* buf0 = ws + OFF_BUF0;
    float* buf1 = ws + OFF_BUF1;
    float* buf2 = ws + OFF_BUF2;
    float* stats = ws + OFF_STATS;
    float* s1S = stats + S1_SUM; float* s1Q = stats + S1_SQ;
    float* s2S = stats + S2_SUM; float* s2Q = stats + S2_SQ;
    float* s3S = stats + S3_SUM; float* s3Q = stats + S3_SQ;
    float* s4S = stats + S4_SUM; float* s4Q = stats + S4_SQ;

    float* out = (float*)d_out;

    // 1) gather + sum-pool -> buf0 = x [2048 x 300]; zero stat buffers
    gather_kernel<<<2048, 128, 0, stream>>>(langs1, sents1, langs2, sents2,
                                            tables, buf0, stats);
    // 2) z1 = x @ w1^T + b1 -> buf1; stats1
    gemm_bn<<<dim3(32, 5), 256, 0, stream>>>(buf0, w1, b1, buf1,
                                             nullptr, nullptr, s1S, s1Q,
                                             2048, 300, 300);
    // 3) z2 = relu(bn1(z1)) @ w2^T + b2 -> buf0; stats2
    gemm_bn<<<dim3(32, 5), 256, 0, stream>>>(buf1, w2, b2, buf0,
                                             s1S, s1Q, s2S, s2Q,
                                             2048, 300, 300);
    // 4) o1,o2 -> d_out; nxt -> buf2
    pair_kernel<<<1024, 128, 0, stream>>>(buf0, s2S, s2Q, out, buf2);
    // 5) y3 = nxt @ w3^T + b3 -> buf1; stats3
    gemm_bn<<<dim3(16, 7), 256, 0, stream>>>(buf2, w3, b3, buf1,
                                             nullptr, nullptr, s3S, s3Q,
                                             1024, 400, 901);
    // 6) y4 = relu(bn3(y3)) @ w4^T + b4 -> buf0; stats4
    gemm_bn<<<dim3(16, 2), 256, 0, stream>>>(buf1, w4, b4, buf0,
                                             s3S, s3Q, s4S, s4Q,
                                             1024, 100, 400);
    // 7) prob -> d_out[0:1024]
    final_kernel<<<1024, 64, 0, stream>>>(buf0, s4S, s4Q, w5, b5, out);
}

// Round 2
// 644.867 us; speedup vs baseline: 1.4447x; 1.4447x over previous
//
#include <hip/hip_runtime.h>
#include <math.h>

#define EPS 1e-5f
#define INV_N (1.0f / 1024.0f)

// out layout: prob[1024] @0, o1[1024*300] @1024, o2 @308224
// All GEMMs run as fp16-input MFMA (fp32 accumulate). K and N padded to
// multiples of 32/64 with zero fill so the MFMA K-loop needs no masking.

typedef _Float16 f16x8 __attribute__((ext_vector_type(8)));
typedef float f32x4 __attribute__((ext_vector_type(4)));

__device__ __forceinline__ _Float16 f2h(float f) { return (_Float16)f; }

static const int STATS_TOTAL = 3400;

// ---------------------------------------------------------------------------
// K1: embedding gather + sum-pool -> xb (f16, K padded 300->320).
// Block 0 zeroes the stat buffers. grid 2048, block 128.
// ---------------------------------------------------------------------------
__global__ __launch_bounds__(128) void gather_kernel(
    const int* __restrict__ langs1, const int* __restrict__ sents1,
    const int* __restrict__ langs2, const int* __restrict__ sents2,
    const float* __restrict__ tables, _Float16* __restrict__ xb,
    float* __restrict__ stats)
{
    int idx = blockIdx.x, t = threadIdx.x;
    if (idx == 0) {
        for (int i = t; i < STATS_TOTAL; i += 128) stats[i] = 0.f;
    }
    int side = idx >> 10, b = idx & 1023;
    const int* langs = side ? langs2 : langs1;
    const int* sents = side ? sents2 : sents1;
    __shared__ int toks[50];
    if (t < 50) toks[t] = sents[b * 50 + t];
    __syncthreads();
    const float* base = tables + (size_t)langs[b] * (200000ull * 300ull);
    float a0 = 0.f, a1 = 0.f, a2 = 0.f;
    #pragma unroll 5
    for (int s = 0; s < 50; s++) {
        const float* row = base + (size_t)toks[s] * 300;
        a0 += row[t];
        a1 += row[t + 128];
        if (t < 44) a2 += row[t + 256];
    }
    _Float16* xr = xb + (size_t)idx * 320;
    xr[t] = f2h(a0);
    xr[t + 128] = f2h(a1);
    if (t < 64) xr[t + 256] = (t < 44) ? f2h(a2) : (_Float16)0.f;
}

// ---------------------------------------------------------------------------
// K2: convert all weights to f16, zero-padded. grid 2632, block 256.
// ---------------------------------------------------------------------------
__global__ __launch_bounds__(256) void wcvt_kernel(
    const float* __restrict__ w1, const float* __restrict__ w2,
    const float* __restrict__ w3, const float* __restrict__ w4,
    _Float16* __restrict__ w1b, _Float16* __restrict__ w2b,
    _Float16* __restrict__ w3b, _Float16* __restrict__ w4b)
{
    int i = blockIdx.x * 256 + threadIdx.x;
    if (i < 102400) {
        int r = i / 320, c = i - r * 320;
        w1b[i] = (r < 300 && c < 300) ? f2h(w1[r * 300 + c]) : (_Float16)0.f;
    } else if (i < 204800) {
        int j = i - 102400; int r = j / 320, c = j - r * 320;
        w2b[j] = (r < 300 && c < 300) ? f2h(w2[r * 300 + c]) : (_Float16)0.f;
    } else if (i < 620544) {
        int j = i - 204800; int r = j / 928, c = j - r * 928;
        w3b[j] = (r < 400 && c < 901) ? f2h(w3[r * 901 + c]) : (_Float16)0.f;
    } else if (i < 673792) {
        int j = i - 620544; int r = j / 416, c = j - r * 416;
        w4b[j] = (r < 100 && c < 400) ? f2h(w4[r * 400 + c]) : (_Float16)0.f;
    }
}

// ---------------------------------------------------------------------------
// MFMA GEMM: C[M][N](fp32) = A[M][Kp](f16) @ W[N][Kp](f16)^T + bias.
// 64x64 block tile, 256 thr = 4 waves (2x2), each wave 32x32 via 2x2
// 16x16x32 frags. LDS seg-major [4 segs][64 rows][8 f16] per operand.
// Column sums/sumsqs of (C+bias) atomically accumulated into sSum/sSq
// (side 1 for rows >= 1024 when twoSided).
// ---------------------------------------------------------------------------
__global__ __launch_bounds__(256) void gemm_f16(
    const _Float16* __restrict__ A, const _Float16* __restrict__ W, int ldk,
    const float* __restrict__ bias, float* __restrict__ C, int ldc,
    int N, int kIters, float* __restrict__ sSum, float* __restrict__ sSq,
    int twoSided)
{
    __shared__ __align__(16) _Float16 lsA[2048];
    __shared__ __align__(16) _Float16 lsW[2048];
    int tid = threadIdx.x;
    int r0 = blockIdx.x * 64, c0 = blockIdx.y * 64;
    int lane = tid & 63;
    int wave = tid >> 6;
    int waveR = wave & 1, waveC = wave >> 1;
    int q = lane >> 4, m = lane & 15;

    int srow = tid >> 2, sseg = tid & 3;
    const _Float16* gA = A + (size_t)(r0 + srow) * ldk + sseg * 8;
    const _Float16* gW = W + (size_t)(c0 + srow) * ldk + sseg * 8;
    _Float16* stA = &lsA[sseg * 512 + srow * 8];
    _Float16* stW = &lsW[sseg * 512 + srow * 8];

    int aoff0 = q * 512 + (waveR * 32 + m) * 8;
    int aoff1 = aoff0 + 128;      // +16 rows
    int boff0 = q * 512 + (waveC * 32 + m) * 8;
    int boff1 = boff0 + 128;

    f32x4 acc00 = {0.f,0.f,0.f,0.f}, acc01 = {0.f,0.f,0.f,0.f};
    f32x4 acc10 = {0.f,0.f,0.f,0.f}, acc11 = {0.f,0.f,0.f,0.f};

    for (int kt = 0; kt < kIters; kt++) {
        uint4 va = *(const uint4*)gA;
        uint4 vw = *(const uint4*)gW;
        gA += 32; gW += 32;
        __syncthreads();                 // prev iter's frag reads done
        *(uint4*)stA = va;
        *(uint4*)stW = vw;
        __syncthreads();
        f16x8 a0 = *(const f16x8*)&lsA[aoff0];
        f16x8 a1 = *(const f16x8*)&lsA[aoff1];
        f16x8 b0 = *(const f16x8*)&lsW[boff0];
        f16x8 b1 = *(const f16x8*)&lsW[boff1];
        acc00 = __builtin_amdgcn_mfma_f32_16x16x32_f16(a0, b0, acc00, 0, 0, 0);
        acc01 = __builtin_amdgcn_mfma_f32_16x16x32_f16(a0, b1, acc01, 0, 0, 0);
        acc10 = __builtin_amdgcn_mfma_f32_16x16x32_f16(a1, b0, acc10, 0, 0, 0);
        acc11 = __builtin_amdgcn_mfma_f32_16x16x32_f16(a1, b1, acc11, 0, 0, 0);
    }

    int side = (twoSided && r0 >= 1024) ? 1 : 0;
    int gc0 = c0 + waveC * 32 + m;
    int gc1 = gc0 + 16;
    float bias0 = (gc0 < N) ? bias[gc0] : 0.f;
    float bias1 = (gc1 < N) ? bias[gc1] : 0.f;
    float colS0 = 0.f, colQ0 = 0.f, colS1 = 0.f, colQ1 = 0.f;
    #pragma unroll
    for (int i = 0; i < 2; i++) {
        f32x4 cv0 = i ? acc10 : acc00;
        f32x4 cv1 = i ? acc11 : acc01;
        #pragma unroll
        for (int r = 0; r < 4; r++) {
            int gr = r0 + waveR * 32 + i * 16 + q * 4 + r;
            if (gc0 < N) {
                float v = cv0[r] + bias0;
                C[(size_t)gr * ldc + gc0] = v;
                colS0 += v; colQ0 += v * v;
            }
            if (gc1 < N) {
                float v = cv1[r] + bias1;
                C[(size_t)gr * ldc + gc1] = v;
                colS1 += v; colQ1 += v * v;
            }
        }
    }
    colS0 += __shfl_down(colS0, 32); colS0 += __shfl_down(colS0, 16);
    colQ0 += __shfl_down(colQ0, 32); colQ0 += __shfl_down(colQ0, 16);
    colS1 += __shfl_down(colS1, 32); colS1 += __shfl_down(colS1, 16);
    colQ1 += __shfl_down(colQ1, 32); colQ1 += __shfl_down(colQ1, 16);
    if (q == 0) {
        if (gc0 < N) {
            atomicAdd(&sSum[side * N + gc0], colS0);
            atomicAdd(&sSq[side * N + gc0], colQ0);
        }
        if (gc1 < N) {
            atomicAdd(&sSum[side * N + gc1], colS1);
            atomicAdd(&sSq[side * N + gc1], colQ1);
        }
    }
}

// ---------------------------------------------------------------------------
// BN+ReLU+cvt: z1[2048][300] -> a1b[2048][320] f16 (2 sides)
// ---------------------------------------------------------------------------
__global__ __launch_bounds__(256) void bncvt1_kernel(
    const float* __restrict__ z, const float* __restrict__ sS,
    const float* __restrict__ sQ, _Float16* __restrict__ out)
{
    int i = blockIdx.x * 256 + threadIdx.x;   // < 655360
    int r = i / 320, c = i - r * 320;
    _Float16 v = (_Float16)0.f;
    if (c < 300) {
        int side = r >> 10;
        float mean = sS[side * 300 + c] * INV_N;
        float var  = sQ[side * 300 + c] * INV_N - mean * mean;
        float x = (z[r * 300 + c] - mean) * rsqrtf(var + EPS);
        v = f2h(fmaxf(x, 0.f));
    }
    out[i] = v;
}

// y3[1024][400] -> a3b[1024][416] f16 (1 side)
__global__ __launch_bounds__(256) void bncvt3_kernel(
    const float* __restrict__ z, const float* __restrict__ sS,
    const float* __restrict__ sQ, _Float16* __restrict__ out)
{
    int i = blockIdx.x * 256 + threadIdx.x;   // < 425984
    int r = i / 416, c = i - r * 416;
    _Float16 v = (_Float16)0.f;
    if (c < 400) {
        float mean = sS[c] * INV_N;
        float var  = sQ[c] * INV_N - mean * mean;
        float x = (z[r * 400 + c] - mean) * rsqrtf(var + EPS);
        v = f2h(fmaxf(x, 0.f));
    }
    out[i] = v;
}

// ---------------------------------------------------------------------------
// BN2+ReLU -> o1,o2 (fp32 to d_out), nxt f16 [1024][928] padded.
// ---------------------------------------------------------------------------
__global__ __launch_bounds__(128) void pair_kernel(
    const float* __restrict__ z2, const float* __restrict__ sS,
    const float* __restrict__ sQ, float* __restrict__ out,
    _Float16* __restrict__ nxtb)
{
    int b = blockIdx.x, t = threadIdx.x;
    __shared__ float red[128];
    float dot = 0.f;
    for (int d = t; d < 300; d += 128) {
        float m1 = sS[d] * INV_N;
        float v1 = sQ[d] * INV_N - m1 * m1;
        float m2 = sS[300 + d] * INV_N;
        float v2 = sQ[300 + d] * INV_N - m2 * m2;
        float a1 = fmaxf((z2[(size_t)b * 300 + d] - m1) * rsqrtf(v1 + EPS), 0.f);
        float a2 = fmaxf((z2[(size_t)(1024 + b) * 300 + d] - m2) * rsqrtf(v2 + EPS), 0.f);
        out[1024 + (size_t)b * 300 + d] = a1;
        out[308224 + (size_t)b * 300 + d] = a2;
        nxtb[(size_t)b * 928 + d] = f2h(a1);
        nxtb[(size_t)b * 928 + 300 + d] = f2h(a2);
        nxtb[(size_t)b * 928 + 600 + d] = f2h(fabsf(a1 - a2));
        dot += a1 * a2;
    }
    red[t] = dot;
    __syncthreads();
    if (t < 27) nxtb[(size_t)b * 928 + 901 + t] = (_Float16)0.f;
    if (t == 0) {
        float s = 0.f;
        for (int i = 0; i < 128; i++) s += red[i];
        nxtb[(size_t)b * 928 + 900] = f2h(s);
    }
}

// ---------------------------------------------------------------------------
// final: BN4+ReLU, dot w5, sigmoid -> prob. grid 1024, block 64.
// ---------------------------------------------------------------------------
__global__ __launch_bounds__(64) void final_kernel(
    const float* __restrict__ y4, const float* __restrict__ sS,
    const float* __restrict__ sQ, const float* __restrict__ w5,
    const float* __restrict__ b5, float* __restrict__ out)
{
    int b = blockIdx.x, l = threadIdx.x;
    float acc = 0.f;
    for (int j = l; j < 100; j += 64) {
        float mean = sS[j] * INV_N;
        float var = sQ[j] * INV_N - mean * mean;
        float v = (y4[(size_t)b * 100 + j] - mean) * rsqrtf(var + EPS);
        v = v > 0.f ? v : 0.f;
        acc += v * w5[j];
    }
    #pragma unroll
    for (int off = 32; off; off >>= 1) acc += __shfl_down(acc, off);
    if (l == 0) out[b] = 1.f / (1.f + expf(-(acc + b5[0])));
}

// ---------------------------------------------------------------------------
extern "C" void kernel_launch(void* const* d_in, const int* in_sizes, int n_in,
                              void* d_out, int out_size, void* d_ws, size_t ws_size,
                              hipStream_t stream)
{
    const int* langs1 = (const int*)d_in[0];
    const int* sents1 = (const int*)d_in[1];
    const int* langs2 = (const int*)d_in[2];
    const int* sents2 = (const int*)d_in[3];
    const float* tables = (const float*)d_in[4];
    const float* w1 = (const float*)d_in[5];
    const float* b1 = (const float*)d_in[6];
    const float* w2 = (const float*)d_in[7];
    const float* b2 = (const float*)d_in[8];
    const float* w3 = (const float*)d_in[9];
    const float* b3 = (const float*)d_in[10];
    const float* w4 = (const float*)d_in[11];
    const float* b4 = (const float*)d_in[12];
    const float* w5 = (const float*)d_in[13];
    const float* b5 = (const float*)d_in[14];

    float* ws = (float*)d_ws;
    float* F0 = ws;
    float* F1 = ws + 614400;
    float* stats = ws + 1228800;
    float* s1S = stats;        float* s1Q = stats + 600;
    float* s2S = stats + 1200; float* s2Q = stats + 1800;
    float* s3S = stats + 2400; float* s3Q = stats + 2800;
    float* s4S = stats + 3200; float* s4Q = stats + 3300;
    _Float16* hb = (_Float16*)(ws + 1232208);
    _Float16* xb   = hb;
    _Float16* a1b  = hb + 655360;
    _Float16* nxtb = hb + 1310720;
    _Float16* a3b  = hb + 2260992;
    _Float16* w1b  = hb + 2686976;
    _Float16* w2b  = hb + 2789376;
    _Float16* w3b  = hb + 2891776;
    _Float16* w4b  = hb + 3307520;

    float* out = (float*)d_out;

    gather_kernel<<<2048, 128, 0, stream>>>(langs1, sents1, langs2, sents2,
                                            tables, xb, stats);
    wcvt_kernel<<<2632, 256, 0, stream>>>(w1, w2, w3, w4, w1b, w2b, w3b, w4b);
    gemm_f16<<<dim3(32, 5), 256, 0, stream>>>(xb, w1b, 320, b1, F0, 300,
                                              300, 10, s1S, s1Q, 1);
    bncvt1_kernel<<<2560, 256, 0, stream>>>(F0, s1S, s1Q, a1b);
    gemm_f16<<<dim3(32, 5), 256, 0, stream>>>(a1b, w2b, 320, b2, F1, 300,
                                              300, 10, s2S, s2Q, 1);
    pair_kernel<<<1024, 128, 0, stream>>>(F1, s2S, s2Q, out, nxtb);
    gemm_f16<<<dim3(16, 7), 256, 0, stream>>>(nxtb, w3b, 928, b3, F0, 400,
                                              400, 29, s3S, s3Q, 0);
    bncvt3_kernel<<<1664, 256, 0, stream>>>(F0, s3S, s3Q, a3b);
    gemm_f16<<<dim3(16, 2), 256, 0, stream>>>(a3b, w4b, 416, b4, F1, 100,
                                              100, 13, s4S, s4Q, 0);
    final_kernel<<<1024, 64, 0, stream>>>(F1, s4S, s4Q, w5, b5, out);
}